// Round 8
// baseline (1213.967 us; speedup 1.0000x reference)
//
#include <hip/hip_runtime.h>
#include <hip/hip_bf16.h>

// GraphCastEdgeBlock fused kernel for MI355X (gfx950).
// h = silu(LN(concat(ea, ns[src], nd[dst]) @ W1 + b1)); out = ea + h @ W2 + b2
// E=600000, N=50000, D=128, H=512, in=384. fp32 I/O; bf16 MFMA compute.
// r7 skeleton (MTILE=64, 8 waves, grid 9375, spill-free) with 32x32x16 MFMA:
// half the MFMA instrs, half the LDS A-reads, 17% faster matrix pipe.

#define E_TOTAL 600000
#define DD      128
#define HH      512
#define IND     384
#define MTILE   64
#define XS      520   // LDS row stride (bf16 elems) for x (384 used) and act (512 used)

typedef __attribute__((ext_vector_type(8)))  short bf16x8;
typedef __attribute__((ext_vector_type(16))) float f32x16;

__device__ __forceinline__ ushort f2bf(float f) {
    __hip_bfloat16 b = __float2bfloat16(f);
    return *reinterpret_cast<ushort*>(&b);
}

template <int CTRL>
__device__ __forceinline__ float dpp_add(float x) {
    union { float f; int i; } a, b;
    a.f = x;
    b.i = __builtin_amdgcn_update_dpp(0, a.i, CTRL, 0xf, 0xf, true);
    return x + b.f;
}
// sum within each 16-lane DPP row; pure VALU
__device__ __forceinline__ float row16_sum(float s) {
    s = dpp_add<0xB1>(s);    // quad_perm xor1
    s = dpp_add<0x4E>(s);    // quad_perm xor2
    s = dpp_add<0x124>(s);   // row_ror:4
    s = dpp_add<0x128>(s);   // row_ror:8
    return s;
}

// W1 [384][512] f32 -> W1t [512][384] bf16 ; W2 [512][128] f32 -> W2t [128][512] bf16
__global__ void prep_weights(const float* __restrict__ W1, const float* __restrict__ W2,
                             ushort* __restrict__ W1t, ushort* __restrict__ W2t) {
    int j = blockIdx.x * 256 + threadIdx.x;
    if (j < IND * HH) {
        int n = j / IND, k = j % IND;
        W1t[j] = f2bf(W1[k * HH + n]);
    }
    int j2 = j - IND * HH;
    if (j2 >= 0 && j2 < HH * DD) {
        int d2 = j2 / HH, k = j2 % HH;
        W2t[j2] = f2bf(W2[k * DD + d2]);
    }
}

__global__ __launch_bounds__(512, 4) void edge_block_kernel(
    const float* __restrict__ edge_attr,
    const float* __restrict__ nsrc,
    const float* __restrict__ ndst,
    const int*   __restrict__ eidx,
    const float* __restrict__ b1,
    const float* __restrict__ g1,
    const float* __restrict__ be1,
    const float* __restrict__ b2,
    const ushort* __restrict__ W1t,
    const ushort* __restrict__ W2t,
    float* __restrict__ out)
{
    __shared__ __align__(16) ushort xbuf[MTILE * XS];  // 66560 B (x, then act)
    __shared__ float red_s[MTILE][8];
    __shared__ float red_q[MTILE][8];
    __shared__ __align__(8) float stats[MTILE][2];

    const int tid  = threadIdx.x;
    const int e0   = blockIdx.x * MTILE;
    const int lane = tid & 63;
    const int w    = tid >> 6;          // wave 0..7
    const int l31  = lane & 31;
    const int hi   = lane >> 5;         // 0/1 (k-half)
    const int hi2  = (lane >> 4) & 1;   // col-half within 32
    const int wm   = w >> 2;            // row half: rows wm*32..+32
    const int wn   = w & 3;             // GEMM1 col quarter: cols wn*128..+128

    // ---- 1) stage x tile [64][384] -> LDS bf16 (stride XS); eidx hoisted ----
    {
        const int l32 = tid & 31, grp = tid >> 5;    // 16 groups of 32 lanes
        int si[4], di[4];
        #pragma unroll
        for (int it = 0; it < 4; ++it) {
            const int e = e0 + grp + it * 16;
            si[it] = eidx[e];
            di[it] = eidx[E_TOTAL + e];
        }
        #pragma unroll
        for (int it = 0; it < 4; ++it) {
            const int r = grp + it * 16;
            const int e = e0 + r;
            float4 ea = *(const float4*)&edge_attr[(size_t)e * DD + l32 * 4];
            float4 sf = *(const float4*)&nsrc[(size_t)si[it] * DD + l32 * 4];
            float4 df = *(const float4*)&ndst[(size_t)di[it] * DD + l32 * 4];
            ushort* row = &xbuf[r * XS];
            ushort4 ua = { f2bf(ea.x), f2bf(ea.y), f2bf(ea.z), f2bf(ea.w) };
            ushort4 us = { f2bf(sf.x), f2bf(sf.y), f2bf(sf.z), f2bf(sf.w) };
            ushort4 ud = { f2bf(df.x), f2bf(df.y), f2bf(df.z), f2bf(df.w) };
            *(ushort4*)&row[  0 + l32 * 4] = ua;
            *(ushort4*)&row[128 + l32 * 4] = us;
            *(ushort4*)&row[256 + l32 * 4] = ud;
        }
    }
    __syncthreads();   // A

    // ---- 2) GEMM1 (32x32x16): wave = rows wm*32..+32, cols wn*128..+128 ----
    f32x16 acc[4];
    #pragma unroll
    for (int nf = 0; nf < 4; ++nf)
        #pragma unroll
        for (int r = 0; r < 16; ++r) acc[nf][r] = 0.f;

    // B frag: col = wn*128 + nf*32 + l31, k = ks*16 + hi*8 + j  (W1t[col][k])
    const ushort* w1p = W1t + (size_t)(wn * 128 + l31) * IND + hi * 8;
    // A frag: row = wm*32 + l31, k = ks*16 + hi*8 + j
    const ushort* xrow = &xbuf[(wm * 32 + l31) * XS + hi * 8];

    bf16x8 B1r[2][4];
    #pragma unroll
    for (int nf = 0; nf < 4; ++nf) B1r[0][nf] = *(const bf16x8*)(w1p + nf * 32 * IND);
    #pragma unroll
    for (int nf = 0; nf < 4; ++nf) B1r[1][nf] = *(const bf16x8*)(w1p + nf * 32 * IND + 16);

    bf16x8 a_[2];
    a_[0] = *(const bf16x8*)(xrow);

    #pragma unroll
    for (int ks = 0; ks < 24; ++ks) {
        const int cur = ks & 1;                    // compile-time after unroll
        if (ks < 23)
            a_[cur ^ 1] = *(const bf16x8*)(xrow + (ks + 1) * 16);
        __builtin_amdgcn_s_setprio(1);
        #pragma unroll
        for (int nf = 0; nf < 4; ++nf)
            acc[nf] = __builtin_amdgcn_mfma_f32_32x32x16_bf16(
                a_[cur], B1r[cur][nf], acc[nf], 0, 0, 0);
        __builtin_amdgcn_s_setprio(0);
        if (ks < 22) {
            #pragma unroll
            for (int nf = 0; nf < 4; ++nf)
                B1r[cur][nf] = *(const bf16x8*)(w1p + nf * 32 * IND + (ks + 2) * 16);
        }
    }

    // ---- 3) bias + row stats; C/D: col = l31, row = (reg&3)+8*(reg>>2)+4*hi ----
    float b1v[4], g1v[4], bev[4];
    #pragma unroll
    for (int nf = 0; nf < 4; ++nf) {
        int c = wn * 128 + nf * 32 + l31;
        b1v[nf] = b1[c]; g1v[nf] = g1[c]; bev[nf] = be1[c];
    }

    #pragma unroll
    for (int reg = 0; reg < 16; ++reg) {
        float s = 0.f, q = 0.f;
        #pragma unroll
        for (int nf = 0; nf < 4; ++nf) {
            float h = acc[nf][reg] + b1v[nf];
            acc[nf][reg] = h;
            s += h;
            q = fmaf(h, h, q);
        }
        s = row16_sum(s);      // partial over 16-col half
        q = row16_sum(q);
        if ((lane & 15) == 0) {
            int row = wm * 32 + (reg & 3) + 8 * (reg >> 2) + 4 * hi;
            red_s[row][wn * 2 + hi2] = s;
            red_q[row][wn * 2 + hi2] = q;
        }
    }
    __syncthreads();   // B

    if (tid < MTILE) {
        float s = 0.f, q = 0.f;
        #pragma unroll
        for (int i = 0; i < 8; ++i) { s += red_s[tid][i]; q += red_q[tid][i]; }
        float mu  = s * (1.f / 512.f);
        float var = q * (1.f / 512.f) - mu * mu;
        stats[tid][0] = mu;
        stats[tid][1] = rsqrtf(var + 1e-5f);
    }
    __syncthreads();   // C

    // ---- 4) LN + SiLU -> act bf16 [64][512] (stride XS, over dead x) ----
    #pragma unroll
    for (int reg = 0; reg < 16; ++reg) {
        int row = wm * 32 + (reg & 3) + 8 * (reg >> 2) + 4 * hi;
        float2 st = *(float2*)&stats[row][0];     // {mu, rstd}
        #pragma unroll
        for (int nf = 0; nf < 4; ++nf) {
            float sc = st.y * g1v[nf];
            float tc = fmaf(-st.x, sc, bev[nf]);
            float xn = fmaf(acc[nf][reg], sc, tc);
            float av = xn * __builtin_amdgcn_rcpf(1.f + __expf(-xn));
            xbuf[row * XS + wn * 128 + nf * 32 + l31] = f2bf(av);
        }
    }

    // residual loads early (latency hides under barrier + GEMM2)
    float earr[16];
    #pragma unroll
    for (int reg = 0; reg < 16; ++reg) {
        int row = wm * 32 + (reg & 3) + 8 * (reg >> 2) + 4 * hi;
        earr[reg] = edge_attr[(size_t)(e0 + row) * DD + wn * 32 + l31];
    }
    __syncthreads();   // D

    // ---- 5) GEMM2 (32x32x16): wave = rows wm*32..+32, out cols wn*32..+32 ----
    // B frag: col = wn*32 + l31, k = ks*16 + hi*8 + j  (W2t[col][k])
    const ushort* w2p = W2t + (size_t)(wn * 32 + l31) * HH + hi * 8;
    const ushort* arow2 = &xbuf[(wm * 32 + l31) * XS + hi * 8];

    bf16x8 B2r[4];
    #pragma unroll
    for (int i = 0; i < 4; ++i) B2r[i] = *(const bf16x8*)(w2p + i * 16);

    f32x16 acc2;
    #pragma unroll
    for (int r = 0; r < 16; ++r) acc2[r] = 0.f;

    bf16x8 a2_[2];
    a2_[0] = *(const bf16x8*)(arow2);

    #pragma unroll
    for (int ks = 0; ks < 32; ++ks) {
        const int cur = ks & 1;
        if (ks < 31)
            a2_[cur ^ 1] = *(const bf16x8*)(arow2 + (ks + 1) * 16);
        acc2 = __builtin_amdgcn_mfma_f32_32x32x16_bf16(a2_[cur], B2r[ks & 3], acc2, 0, 0, 0);
        if (ks < 28)
            B2r[ks & 3] = *(const bf16x8*)(w2p + (ks + 4) * 16);
    }

    // ---- 6) epilogue: out = acc2 + b2 + ea(regs); 128B-contig per 32 lanes ----
    const float b2v = b2[wn * 32 + l31];
    #pragma unroll
    for (int reg = 0; reg < 16; ++reg) {
        int row = wm * 32 + (reg & 3) + 8 * (reg >> 2) + 4 * hi;
        size_t o = (size_t)(e0 + row) * DD + wn * 32 + l31;
        out[o] = acc2[reg] + b2v + earr[reg];
    }
}

extern "C" void kernel_launch(void* const* d_in, const int* in_sizes, int n_in,
                              void* d_out, int out_size, void* d_ws, size_t ws_size,
                              hipStream_t stream) {
    const float* edge_attr = (const float*)d_in[0];
    const float* nsrc      = (const float*)d_in[1];
    const float* ndst      = (const float*)d_in[2];
    const int*   eidx      = (const int*)d_in[3];
    const float* W1        = (const float*)d_in[4];
    const float* b1        = (const float*)d_in[5];
    const float* g1        = (const float*)d_in[6];
    const float* be1       = (const float*)d_in[7];
    const float* W2        = (const float*)d_in[8];
    const float* b2        = (const float*)d_in[9];
    float* out = (float*)d_out;

    ushort* W1t = (ushort*)d_ws;             // 512*384 bf16 = 384 KiB
    ushort* W2t = W1t + IND * HH;            // 128*512 bf16 = 128 KiB

    hipLaunchKernelGGL(prep_weights,
                       dim3((IND * HH + HH * DD + 255) / 256), dim3(256), 0, stream,
                       W1, W2, W1t, W2t);

    hipLaunchKernelGGL(edge_block_kernel,
                       dim3(E_TOTAL / MTILE), dim3(512), 0, stream,
                       edge_attr, nsrc, ndst, eidx, b1, g1, be1, b2, W1t, W2t, out);
}

// Round 9
// 937.806 us; speedup vs baseline: 1.2945x; 1.2945x over previous
//
#include <hip/hip_runtime.h>
#include <hip/hip_bf16.h>

// GraphCastEdgeBlock fused kernel for MI355X (gfx950).
// h = silu(LN(concat(ea, ns[src], nd[dst]) @ W1 + b1)); out = ea + h @ W2 + b2
// E=600000, N=50000, D=128, H=512, in=384. fp32 I/O; bf16 MFMA compute.
// r7 skeleton (MTILE=64, 8 waves, 16x16x32 MFMA, spill-free) +
// 16B-chunk XOR-swizzled LDS (conflict-free A reads) + earlier earr/B2 issue.

#define E_TOTAL 600000
#define DD      128
#define HH      512
#define IND     384
#define MTILE   64

typedef __attribute__((ext_vector_type(8))) short bf16x8;
typedef __attribute__((ext_vector_type(4))) float f32x4;

__device__ __forceinline__ ushort f2bf(float f) {
    __hip_bfloat16 b = __float2bfloat16(f);
    return *reinterpret_cast<ushort*>(&b);
}

template <int CTRL>
__device__ __forceinline__ float dpp_add(float x) {
    union { float f; int i; } a, b;
    a.f = x;
    b.i = __builtin_amdgcn_update_dpp(0, a.i, CTRL, 0xf, 0xf, true);
    return x + b.f;
}
// sum across each 16-lane row (all lanes get the sum); pure VALU, no DS
__device__ __forceinline__ float row16_sum(float s) {
    s = dpp_add<0xB1>(s);    // quad_perm xor1
    s = dpp_add<0x4E>(s);    // quad_perm xor2
    s = dpp_add<0x124>(s);   // row_ror:4
    s = dpp_add<0x128>(s);   // row_ror:8
    return s;
}

// W1 [384][512] f32 -> W1t [512][384] bf16 ; W2 [512][128] f32 -> W2t [128][512] bf16
__global__ void prep_weights(const float* __restrict__ W1, const float* __restrict__ W2,
                             ushort* __restrict__ W1t, ushort* __restrict__ W2t) {
    int j = blockIdx.x * 256 + threadIdx.x;
    if (j < IND * HH) {
        int n = j / IND, k = j % IND;
        W1t[j] = f2bf(W1[k * HH + n]);
    }
    int j2 = j - IND * HH;
    if (j2 >= 0 && j2 < HH * DD) {
        int d2 = j2 / HH, k = j2 % HH;
        W2t[j2] = f2bf(W2[k * DD + d2]);
    }
}

__global__ __launch_bounds__(512, 4) void edge_block_kernel(
    const float* __restrict__ edge_attr,
    const float* __restrict__ nsrc,
    const float* __restrict__ ndst,
    const int*   __restrict__ eidx,
    const float* __restrict__ b1,
    const float* __restrict__ g1,
    const float* __restrict__ be1,
    const float* __restrict__ b2,
    const ushort* __restrict__ W1t,
    const ushort* __restrict__ W2t,
    float* __restrict__ out)
{
    // act [64][512] overlays x [64][384]; both pad-free, 16B-chunk XOR swizzle
    __shared__ __align__(16) ushort xbuf[MTILE * 512];   // 65536 B
    __shared__ float red_s[MTILE][8];
    __shared__ float red_q[MTILE][8];
    __shared__ __align__(8) float stats[MTILE][2];

    const int tid  = threadIdx.x;
    const int e0   = blockIdx.x * MTILE;
    const int lane = tid & 63;
    const int w    = tid >> 6;          // wave 0..7
    const int g    = lane >> 4;         // quarter-wave 0..3
    const int li   = lane & 15;
    const int sx   = li & 7;            // row&7 for rows mi*16+li

    // ---- 1) stage x tile [64][384] -> LDS bf16 (swizzled); eidx hoisted ----
    {
        const int l32 = tid & 31, grp = tid >> 5;    // 16 groups of 32 lanes
        int si[4], di[4];
        #pragma unroll
        for (int it = 0; it < 4; ++it) {
            const int e = e0 + grp + it * 16;
            si[it] = eidx[e];
            di[it] = eidx[E_TOTAL + e];
        }
        const int ch = l32 >> 1;                     // 16B-chunk within 128-col third
        const int off8 = (l32 & 1) * 4;              // ushort offset within chunk
        #pragma unroll
        for (int it = 0; it < 4; ++it) {
            const int r = grp + it * 16;
            const int e = e0 + r;
            const int rs = r & 7;
            float4 ea = *(const float4*)&edge_attr[(size_t)e * DD + l32 * 4];
            float4 sf = *(const float4*)&nsrc[(size_t)si[it] * DD + l32 * 4];
            float4 df = *(const float4*)&ndst[(size_t)di[it] * DD + l32 * 4];
            ushort* row = &xbuf[r * IND];
            ushort4 ua = { f2bf(ea.x), f2bf(ea.y), f2bf(ea.z), f2bf(ea.w) };
            ushort4 us = { f2bf(sf.x), f2bf(sf.y), f2bf(sf.z), f2bf(sf.w) };
            ushort4 ud = { f2bf(df.x), f2bf(df.y), f2bf(df.z), f2bf(df.w) };
            *(ushort4*)&row[(((ch     ) ^ rs) << 3) + off8] = ua;   // cols 0..127
            *(ushort4*)&row[(((ch + 16) ^ rs) << 3) + off8] = us;   // cols 128..255
            *(ushort4*)&row[(((ch + 32) ^ rs) << 3) + off8] = ud;   // cols 256..383
        }
    }
    __syncthreads();   // A

    // ---- 2) GEMM1: h[64][512] = x @ W1; wave w owns cols [w*64, w*64+64) ----
    const int wn0 = w * 64;
    f32x4 acc[4][4];
    #pragma unroll
    for (int mi = 0; mi < 4; ++mi)
        #pragma unroll
        for (int ni = 0; ni < 4; ++ni)
            acc[mi][ni] = (f32x4){0.f, 0.f, 0.f, 0.f};

    const ushort* w1p = W1t + (size_t)(wn0 + li) * IND + g * 8;

    bf16x8 B1b[2][4];
    #pragma unroll
    for (int ni = 0; ni < 4; ++ni) B1b[0][ni] = *(const bf16x8*)(w1p + ni * 16 * IND);
    #pragma unroll
    for (int ni = 0; ni < 4; ++ni) B1b[1][ni] = *(const bf16x8*)(w1p + ni * 16 * IND + 32);

    #pragma unroll
    for (int kb = 0; kb < 12; ++kb) {
        const int cur = kb & 1;                  // compile-time after unroll
        const int swc = ((kb * 4 + g) ^ sx) << 3;   // swizzled chunk offset (ushorts)
        bf16x8 a[4];
        #pragma unroll
        for (int mi = 0; mi < 4; ++mi)
            a[mi] = *(const bf16x8*)&xbuf[(mi * 16 + li) * IND + swc];
        __builtin_amdgcn_s_setprio(1);
        #pragma unroll
        for (int mi = 0; mi < 4; ++mi)
            #pragma unroll
            for (int ni = 0; ni < 4; ++ni)
                acc[mi][ni] = __builtin_amdgcn_mfma_f32_16x16x32_bf16(
                    a[mi], B1b[cur][ni], acc[mi][ni], 0, 0, 0);
        __builtin_amdgcn_s_setprio(0);
        if (kb < 10) {                           // prefetch depth 2
            #pragma unroll
            for (int ni = 0; ni < 4; ++ni)
                B1b[cur][ni] = *(const bf16x8*)(w1p + ni * 16 * IND + (kb + 2) * 32);
        }
    }

    // ---- 3) bias + row stats via DPP row-reduce ----
    float b1v[4], g1v[4], bev[4];
    #pragma unroll
    for (int ni = 0; ni < 4; ++ni) {
        int c = wn0 + ni * 16 + li;
        b1v[ni] = b1[c]; g1v[ni] = g1[c]; bev[ni] = be1[c];
    }

    #pragma unroll
    for (int mi = 0; mi < 4; ++mi) {
        #pragma unroll
        for (int reg = 0; reg < 4; ++reg) {
            float s = 0.f, q = 0.f;
            #pragma unroll
            for (int ni = 0; ni < 4; ++ni) {
                float h = acc[mi][ni][reg] + b1v[ni];
                acc[mi][ni][reg] = h;
                s += h;
                q = fmaf(h, h, q);
            }
            s = row16_sum(s);
            q = row16_sum(q);
            if (li == 0) {
                int row = mi * 16 + g * 4 + reg;
                red_s[row][w] = s;
                red_q[row][w] = q;
            }
        }
    }

    // residual loads issued 2 phases early; consumed in epilogue
    float earr[4][4];
    #pragma unroll
    for (int mi = 0; mi < 4; ++mi)
        #pragma unroll
        for (int reg = 0; reg < 4; ++reg) {
            int row = mi * 16 + g * 4 + reg;
            earr[mi][reg] = edge_attr[(size_t)(e0 + row) * DD + w * 16 + li];
        }
    __syncthreads();   // B

    // B2 ring-4 preload issued 1 phase early (lands during stats + LN)
    const ushort* w2p = W2t + (size_t)(w * 16 + li) * HH + g * 8;
    bf16x8 B2r[4];
    #pragma unroll
    for (int i = 0; i < 4; ++i) B2r[i] = *(const bf16x8*)(w2p + i * 32);

    if (tid < MTILE) {
        float s = 0.f, q = 0.f;
        #pragma unroll
        for (int i = 0; i < 8; ++i) { s += red_s[tid][i]; q += red_q[tid][i]; }
        float mu  = s * (1.f / 512.f);
        float var = q * (1.f / 512.f) - mu * mu;
        stats[tid][0] = mu;
        stats[tid][1] = rsqrtf(var + 1e-5f);
    }
    __syncthreads();   // C

    // ---- 4) LN + SiLU -> act bf16 [64][512] swizzled (x region is dead) ----
    #pragma unroll
    for (int mi = 0; mi < 4; ++mi) {
        #pragma unroll
        for (int reg = 0; reg < 4; ++reg) {
            int row = mi * 16 + g * 4 + reg;
            int rs  = row & 7;
            float2 st = *(float2*)&stats[row][0];     // {mu, rstd}
            ushort* arow = &xbuf[row * HH];
            #pragma unroll
            for (int ni = 0; ni < 4; ++ni) {
                float sc = st.y * g1v[ni];                       // rstd*gamma
                float tc = fmaf(-st.x, sc, bev[ni]);             // beta - mu*sc
                float xn = fmaf(acc[mi][ni][reg], sc, tc);
                float ex = __expf(-xn);
                float av = xn * __builtin_amdgcn_rcpf(1.f + ex); // silu
                int col = wn0 + ni * 16 + li;
                arow[(((col >> 3) ^ rs) << 3) + (col & 7)] = f2bf(av);
            }
        }
    }
    __syncthreads();   // D

    // ---- 5) GEMM2: out[64][128] = act @ W2; ring-4 streamed B ----
    f32x4 acc2[4];
    #pragma unroll
    for (int mi = 0; mi < 4; ++mi) acc2[mi] = (f32x4){0.f, 0.f, 0.f, 0.f};

    #pragma unroll
    for (int kb = 0; kb < 16; ++kb) {
        const int cur = kb & 3;                  // compile-time after unroll
        bf16x8 bf = B2r[cur];
        if (kb < 12)
            B2r[cur] = *(const bf16x8*)(w2p + (kb + 4) * 32);
        const int swc = ((kb * 4 + g) ^ sx) << 3;
        bf16x8 a2[4];
        #pragma unroll
        for (int mi = 0; mi < 4; ++mi)
            a2[mi] = *(const bf16x8*)&xbuf[(mi * 16 + li) * HH + swc];
        __builtin_amdgcn_s_setprio(1);
        #pragma unroll
        for (int mi = 0; mi < 4; ++mi)
            acc2[mi] = __builtin_amdgcn_mfma_f32_16x16x32_bf16(a2[mi], bf, acc2[mi], 0, 0, 0);
        __builtin_amdgcn_s_setprio(0);
    }

    // ---- 6) epilogue: direct stores, out = acc2 + b2 + ea(regs) ----
    const float b2v = b2[w * 16 + li];
    #pragma unroll
    for (int mi = 0; mi < 4; ++mi) {
        #pragma unroll
        for (int reg = 0; reg < 4; ++reg) {
            int row = mi * 16 + g * 4 + reg;
            size_t o = (size_t)(e0 + row) * DD + w * 16 + li;
            out[o] = acc2[mi][reg] + b2v + earr[mi][reg];
        }
    }
}

extern "C" void kernel_launch(void* const* d_in, const int* in_sizes, int n_in,
                              void* d_out, int out_size, void* d_ws, size_t ws_size,
                              hipStream_t stream) {
    const float* edge_attr = (const float*)d_in[0];
    const float* nsrc      = (const float*)d_in[1];
    const float* ndst      = (const float*)d_in[2];
    const int*   eidx      = (const int*)d_in[3];
    const float* W1        = (const float*)d_in[4];
    const float* b1        = (const float*)d_in[5];
    const float* g1        = (const float*)d_in[6];
    const float* be1       = (const float*)d_in[7];
    const float* W2        = (const float*)d_in[8];
    const float* b2        = (const float*)d_in[9];
    float* out = (float*)d_out;

    ushort* W1t = (ushort*)d_ws;             // 512*384 bf16 = 384 KiB
    ushort* W2t = W1t + IND * HH;            // 128*512 bf16 = 128 KiB

    hipLaunchKernelGGL(prep_weights,
                       dim3((IND * HH + HH * DD + 255) / 256), dim3(256), 0, stream,
                       W1, W2, W1t, W2t);

    hipLaunchKernelGGL(edge_block_kernel,
                       dim3(E_TOTAL / MTILE), dim3(512), 0, stream,
                       edge_attr, nsrc, ndst, eidx, b1, g1, be1, b2, W1t, W2t, out);
}

// Round 10
// 741.068 us; speedup vs baseline: 1.6381x; 1.2655x over previous
//
#include <hip/hip_runtime.h>
#include <hip/hip_bf16.h>

// GraphCastEdgeBlock fused kernel for MI355X (gfx950).
// h = silu(LN(concat(ea, ns[src], nd[dst]) @ W1 + b1)); out = ea + h @ W2 + b2
// E=600000, N=50000, D=128, H=512, in=384. fp32 I/O; bf16 MFMA compute.
// r7 skeleton (MTILE=64, 8 waves, 16x16x32, spill-free ordering) +
// 16B-chunk XOR-swizzled pad-free LDS + pair-packed act writes (cvt_pk,
// b32 coalesced, conflict-free) with matching k-permutation baked into W2t.

#define E_TOTAL 600000
#define DD      128
#define HH      512
#define IND     384
#define MTILE   64

typedef __attribute__((ext_vector_type(8))) short bf16x8;
typedef __attribute__((ext_vector_type(4))) float f32x4;

__device__ __forceinline__ ushort f2bf(float f) {
    __hip_bfloat16 b = __float2bfloat16(f);
    return *reinterpret_cast<ushort*>(&b);
}
// pack two f32 -> one u32 of 2 bf16 (lo = a, hi = b); native -> v_cvt_pk_bf16_f32
__device__ __forceinline__ uint pk2(float a, float b) {
    __hip_bfloat162 h = __float22bfloat162_rn(float2{a, b});
    return *reinterpret_cast<uint*>(&h);
}

template <int CTRL>
__device__ __forceinline__ float dpp_add(float x) {
    union { float f; int i; } a, b;
    a.f = x;
    b.i = __builtin_amdgcn_update_dpp(0, a.i, CTRL, 0xf, 0xf, true);
    return x + b.f;
}
// sum across each 16-lane row (all lanes get the sum); pure VALU, no DS
__device__ __forceinline__ float row16_sum(float s) {
    s = dpp_add<0xB1>(s);    // quad_perm xor1
    s = dpp_add<0x4E>(s);    // quad_perm xor2
    s = dpp_add<0x124>(s);   // row_ror:4
    s = dpp_add<0x128>(s);   // row_ror:8
    return s;
}

// W1 [384][512] f32 -> W1t [512][384] bf16 (plain transpose).
// W2 [512][128] f32 -> W2t [128][512] bf16 with k-PERMUTED columns:
// j = b64*64 + q*32 + li*2 + lo  <->  k = b64*64 + (q*2+lo)*16 + li
// (matches LN's pair-packed act layout).
__global__ void prep_weights(const float* __restrict__ W1, const float* __restrict__ W2,
                             ushort* __restrict__ W1t, ushort* __restrict__ W2t) {
    int j = blockIdx.x * 256 + threadIdx.x;
    if (j < IND * HH) {
        int n = j / IND, k = j % IND;
        W1t[j] = f2bf(W1[k * HH + n]);
    }
    int j2 = j - IND * HH;
    if (j2 >= 0 && j2 < HH * DD) {
        int d2 = j2 / HH, jj = j2 % HH;
        int b64 = jj >> 6, r6 = jj & 63;
        int q = r6 >> 5, r5 = r6 & 31;
        int li = r5 >> 1, lo = r5 & 1;
        int k = b64 * 64 + (q * 2 + lo) * 16 + li;
        W2t[j2] = f2bf(W2[k * DD + d2]);
    }
}

__global__ __launch_bounds__(512, 4) void edge_block_kernel(
    const float* __restrict__ edge_attr,
    const float* __restrict__ nsrc,
    const float* __restrict__ ndst,
    const int*   __restrict__ eidx,
    const float* __restrict__ b1,
    const float* __restrict__ g1,
    const float* __restrict__ be1,
    const float* __restrict__ b2,
    const ushort* __restrict__ W1t,
    const ushort* __restrict__ W2t,
    float* __restrict__ out)
{
    // act [64][512] bf16 overlays x [64][384] bf16; pad-free, 16B-chunk XOR swizzle
    __shared__ __align__(16) ushort xbuf[MTILE * 512];   // 65536 B
    __shared__ float red_s[MTILE][8];
    __shared__ float red_q[MTILE][8];
    __shared__ __align__(8) float stats[MTILE][2];

    const int tid  = threadIdx.x;
    const int e0   = blockIdx.x * MTILE;
    const int lane = tid & 63;
    const int w    = tid >> 6;          // wave 0..7
    const int g    = lane >> 4;         // quarter-wave 0..3
    const int li   = lane & 15;
    const int sx   = li & 7;            // row&7 for rows mi*16+li

    // ---- 1) stage x tile [64][384] -> LDS bf16 (swizzled, pk2 packed) ----
    {
        const int l32 = tid & 31, grp = tid >> 5;    // 16 groups of 32 lanes
        int si[4], di[4];
        #pragma unroll
        for (int it = 0; it < 4; ++it) {
            const int e = e0 + grp + it * 16;
            si[it] = eidx[e];
            di[it] = eidx[E_TOTAL + e];
        }
        const int ch = l32 >> 1;                     // 16B chunk within 128-col region
        const int off8 = (l32 & 1) * 4;              // ushort offset within chunk
        #pragma unroll
        for (int it = 0; it < 4; ++it) {
            const int r = grp + it * 16;
            const int e = e0 + r;
            const int rs = r & 7;
            float4 ea = *(const float4*)&edge_attr[(size_t)e * DD + l32 * 4];
            float4 sf = *(const float4*)&nsrc[(size_t)si[it] * DD + l32 * 4];
            float4 df = *(const float4*)&ndst[(size_t)di[it] * DD + l32 * 4];
            ushort* row = &xbuf[r * IND];
            uint2 ua = { pk2(ea.x, ea.y), pk2(ea.z, ea.w) };
            uint2 us = { pk2(sf.x, sf.y), pk2(sf.z, sf.w) };
            uint2 ud = { pk2(df.x, df.y), pk2(df.z, df.w) };
            *(uint2*)&row[(((ch     ) ^ rs) << 3) + off8] = ua;   // cols 0..127
            *(uint2*)&row[(((ch + 16) ^ rs) << 3) + off8] = us;   // cols 128..255
            *(uint2*)&row[(((ch + 32) ^ rs) << 3) + off8] = ud;   // cols 256..383
        }
    }
    __syncthreads();   // A

    // ---- 2) GEMM1: h[64][512] = x @ W1; wave w owns cols [w*64, w*64+64) ----
    const int wn0 = w * 64;
    f32x4 acc[4][4];
    #pragma unroll
    for (int mi = 0; mi < 4; ++mi)
        #pragma unroll
        for (int ni = 0; ni < 4; ++ni)
            acc[mi][ni] = (f32x4){0.f, 0.f, 0.f, 0.f};

    const ushort* w1p = W1t + (size_t)(wn0 + li) * IND + g * 8;

    bf16x8 B1b[2][4];
    #pragma unroll
    for (int ni = 0; ni < 4; ++ni) B1b[0][ni] = *(const bf16x8*)(w1p + ni * 16 * IND);
    #pragma unroll
    for (int ni = 0; ni < 4; ++ni) B1b[1][ni] = *(const bf16x8*)(w1p + ni * 16 * IND + 32);

    #pragma unroll
    for (int kb = 0; kb < 12; ++kb) {
        const int cur = kb & 1;                     // compile-time after unroll
        const int swc = ((kb * 4 + g) ^ sx) << 3;   // swizzled chunk offset (ushorts)
        bf16x8 a[4];
        #pragma unroll
        for (int mi = 0; mi < 4; ++mi)
            a[mi] = *(const bf16x8*)&xbuf[(mi * 16 + li) * IND + swc];
        __builtin_amdgcn_s_setprio(1);
        #pragma unroll
        for (int mi = 0; mi < 4; ++mi)
            #pragma unroll
            for (int ni = 0; ni < 4; ++ni)
                acc[mi][ni] = __builtin_amdgcn_mfma_f32_16x16x32_bf16(
                    a[mi], B1b[cur][ni], acc[mi][ni], 0, 0, 0);
        __builtin_amdgcn_s_setprio(0);
        if (kb < 10) {                              // prefetch depth 2
            #pragma unroll
            for (int ni = 0; ni < 4; ++ni)
                B1b[cur][ni] = *(const bf16x8*)(w1p + ni * 16 * IND + (kb + 2) * 32);
        }
    }

    // ---- 3) bias + row stats via DPP row-reduce ----
    float b1v[4], g1v[4], bev[4];
    #pragma unroll
    for (int ni = 0; ni < 4; ++ni) {
        int c = wn0 + ni * 16 + li;
        b1v[ni] = b1[c]; g1v[ni] = g1[c]; bev[ni] = be1[c];
    }

    #pragma unroll
    for (int mi = 0; mi < 4; ++mi) {
        #pragma unroll
        for (int reg = 0; reg < 4; ++reg) {
            float s = 0.f, q = 0.f;
            #pragma unroll
            for (int ni = 0; ni < 4; ++ni) {
                float h = acc[mi][ni][reg] + b1v[ni];
                acc[mi][ni][reg] = h;
                s += h;
                q = fmaf(h, h, q);
            }
            s = row16_sum(s);
            q = row16_sum(q);
            if (li == 0) {
                int row = mi * 16 + g * 4 + reg;
                red_s[row][w] = s;
                red_q[row][w] = q;
            }
        }
    }
    __syncthreads();   // B

    if (tid < MTILE) {
        float s = 0.f, q = 0.f;
        #pragma unroll
        for (int i = 0; i < 8; ++i) { s += red_s[tid][i]; q += red_q[tid][i]; }
        float mu  = s * (1.f / 512.f);
        float var = q * (1.f / 512.f) - mu * mu;
        stats[tid][0] = mu;
        stats[tid][1] = rsqrtf(var + 1e-5f);
    }
    __syncthreads();   // C

    // ---- 4) B2 ring-4 preload (16 VGPR; r7 placement) ----
    const ushort* w2p = W2t + (size_t)(w * 16 + li) * HH + g * 8;
    bf16x8 B2r[4];
    #pragma unroll
    for (int i = 0; i < 4; ++i) B2r[i] = *(const bf16x8*)(w2p + i * 32);

    // ---- 5) LN + SiLU -> act, pair-packed b32 swizzled writes ----
    uint* actu = (uint*)xbuf;
    #pragma unroll
    for (int mi = 0; mi < 4; ++mi) {
        #pragma unroll
        for (int reg = 0; reg < 4; ++reg) {
            int row = mi * 16 + g * 4 + reg;
            int rs  = row & 7;
            float2 st = *(float2*)&stats[row][0];     // {mu, rstd}
            uint* arow = actu + row * 256;
            #pragma unroll
            for (int p = 0; p < 2; ++p) {
                float av[2];
                #pragma unroll
                for (int lo = 0; lo < 2; ++lo) {
                    int ni = p * 2 + lo;
                    float sc = st.y * g1v[ni];                       // rstd*gamma
                    float tc = fmaf(-st.x, sc, bev[ni]);             // beta - mu*sc
                    float xn = fmaf(acc[mi][ni][reg], sc, tc);
                    float ex = __expf(-xn);
                    av[lo] = xn * __builtin_amdgcn_rcpf(1.f + ex);   // silu
                }
                // permuted k': j = w*32 + p*16 + li (u32 index within row)
                int j = (wn0 >> 1) + p * 16 + li;
                int c = j >> 2, wi = j & 3;
                arow[((c ^ rs) << 2) + wi] = pk2(av[0], av[1]);
            }
        }
    }

    // residual loads (r7 placement: after LN, before barrier D)
    float earr[4][4];
    #pragma unroll
    for (int mi = 0; mi < 4; ++mi)
        #pragma unroll
        for (int reg = 0; reg < 4; ++reg) {
            int row = mi * 16 + g * 4 + reg;
            earr[mi][reg] = edge_attr[(size_t)(e0 + row) * DD + w * 16 + li];
        }
    __syncthreads();   // D

    // ---- 6) GEMM2: out[64][128] = act @ W2 (permuted k, same swizzle) ----
    f32x4 acc2[4];
    #pragma unroll
    for (int mi = 0; mi < 4; ++mi) acc2[mi] = (f32x4){0.f, 0.f, 0.f, 0.f};

    #pragma unroll
    for (int kb = 0; kb < 16; ++kb) {
        const int cur = kb & 3;                  // compile-time after unroll
        bf16x8 bf = B2r[cur];
        if (kb < 12)
            B2r[cur] = *(const bf16x8*)(w2p + (kb + 4) * 32);
        const int swc = ((kb * 4 + g) ^ sx) << 3;
        bf16x8 a2[4];
        #pragma unroll
        for (int mi = 0; mi < 4; ++mi)
            a2[mi] = *(const bf16x8*)&xbuf[(mi * 16 + li) * HH + swc];
        __builtin_amdgcn_s_setprio(1);
        #pragma unroll
        for (int mi = 0; mi < 4; ++mi)
            acc2[mi] = __builtin_amdgcn_mfma_f32_16x16x32_bf16(a2[mi], bf, acc2[mi], 0, 0, 0);
        __builtin_amdgcn_s_setprio(0);
    }

    // ---- 7) epilogue: direct stores, out = acc2 + b2 + ea(regs) ----
    const float b2v = b2[w * 16 + li];
    #pragma unroll
    for (int mi = 0; mi < 4; ++mi) {
        #pragma unroll
        for (int reg = 0; reg < 4; ++reg) {
            int row = mi * 16 + g * 4 + reg;
            size_t o = (size_t)(e0 + row) * DD + w * 16 + li;
            out[o] = acc2[mi][reg] + b2v + earr[mi][reg];
        }
    }
}

extern "C" void kernel_launch(void* const* d_in, const int* in_sizes, int n_in,
                              void* d_out, int out_size, void* d_ws, size_t ws_size,
                              hipStream_t stream) {
    const float* edge_attr = (const float*)d_in[0];
    const float* nsrc      = (const float*)d_in[1];
    const float* ndst      = (const float*)d_in[2];
    const int*   eidx      = (const int*)d_in[3];
    const float* W1        = (const float*)d_in[4];
    const float* b1        = (const float*)d_in[5];
    const float* g1        = (const float*)d_in[6];
    const float* be1       = (const float*)d_in[7];
    const float* W2        = (const float*)d_in[8];
    const float* b2        = (const float*)d_in[9];
    float* out = (float*)d_out;

    ushort* W1t = (ushort*)d_ws;             // 512*384 bf16 = 384 KiB
    ushort* W2t = W1t + IND * HH;            // 128*512 bf16 = 128 KiB

    hipLaunchKernelGGL(prep_weights,
                       dim3((IND * HH + HH * DD + 255) / 256), dim3(256), 0, stream,
                       W1, W2, W1t, W2t);

    hipLaunchKernelGGL(edge_block_kernel,
                       dim3(E_TOTAL / MTILE), dim3(512), 0, stream,
                       edge_attr, nsrc, ndst, eidx, b1, g1, be1, b2, W1t, W2t, out);
}